// Round 2
// baseline (294.778 us; speedup 1.0000x reference)
//
#include <hip/hip_runtime.h>
#include <stdint.h>

#define N_ROWS   16384
#define IN_DIM   512
#define CB_DIM   16
#define CB_VOCAB 8192

// ---- K1 geometry
#define PROJ_BLOCKS 256                          // 64 rows each (2 rows/lane), full K
#define PREP_BLOCKS 128                          // 4 code-tiles each

// ---- scan geometry
#define N_RT   (N_ROWS / 16)                     // 1024 row-tiles
#define N_CT   (CB_VOCAB / 16)                   // 512 code-tiles
#define CODEPARTS 32
#define CT_PER_PART (N_CT / CODEPARTS)           // 16
#define N_ROWGRP 64                              // 256 rows per rowgrp

// ---- workspace layout (bytes), ~3.2 MB
#define WS_OFF_AFA  0                            // A-frag [A1|A2]: 1 MB
#define WS_OFF_AFB  (1u << 20)                   // A-frag [A1|A3]: 1 MB
#define WS_OFF_BHH  (2u << 20)                   // B-frag [B1;B2]: 512 KB
#define WS_OFF_B31  ((2u << 20) + (512u << 10))  // B-frag [B3;B1]: 512 KB
#define WS_OFF_PART (3u << 20)                   // u64[16384]: 128 KB
#define WS_OFF_CNT  ((3u << 20) + (128u << 10))  // u32[64]

typedef __attribute__((ext_vector_type(8))) short bf16x8;
typedef __attribute__((ext_vector_type(4))) float f32x4;

// monotone float -> uint32 key (order-preserving)
__device__ __forceinline__ unsigned fkey(float f) {
    unsigned u = __float_as_uint(f);
    return (u & 0x80000000u) ? ~u : (u | 0x80000000u);
}

// fp32 -> bf16 bits, round-to-nearest-even
__device__ __forceinline__ unsigned short f2bf(float f) {
    unsigned u = __float_as_uint(f);
    return (unsigned short)((u + 0x7FFFu + ((u >> 16) & 1u)) >> 16);
}
__device__ __forceinline__ float bf2f(unsigned short h) {
    return __uint_as_float(((unsigned)h) << 16);
}

// ---------------- K1: proj + fold + A-frag (blocks 0..255); CB prep + init
// (blocks 256..383).
// proj: block = 64 rows x full K=512, 2 rows per lane (halves the per-row
// LDS broadcast-read pressure: each Ps read feeds 2 FMAs). Wave w, lane-half
// h cover k in [128w+64h, +64); lane owns rows r32 and r32+32. 8 k-partials
// in LDS, folded in-block (4 row-tiles, one per wave), 3-way bf16 split,
// A-frags written directly.
__global__ __launch_bounds__(256, 2)
void k_front(const float* __restrict__ x, const float* __restrict__ P,
             const float* __restrict__ CB,
             bf16x8* __restrict__ AfragA, bf16x8* __restrict__ AfragB,
             bf16x8* __restrict__ Bhh, bf16x8* __restrict__ B31,
             unsigned long long* __restrict__ part, unsigned* __restrict__ cnt) {
    __shared__ float4 Ps[IN_DIM * 4];            // P [512][16]: 32 KB
    __shared__ float  accs[8][64][20];           // 8 k-partials x 64 rows: 40 KB

    const int wave = threadIdx.x >> 6;
    const int lane = threadIdx.x & 63;

    if (blockIdx.x >= PROJ_BLOCKS) {
        // ---- prep path: zero part/cnt, build CB B-frags ----
        const int pb = blockIdx.x - PROJ_BLOCKS;
        if (threadIdx.x < 128) part[pb * 128 + threadIdx.x] = 0ull;
        if (pb == 0 && threadIdx.x < 64) cnt[threadIdx.x] = 0u;

        const int ct   = pb * 4 + wave;
        const int n    = lane & 15;
        const int quad = lane >> 4;
        const int kh   = (quad & 1) * 8;
        const int lvl  = quad >> 1;
        const int code = ct * 16 + n;

        const float4* b4 = (const float4*)(CB + (size_t)code * CB_DIM + kh);
        float4 a = b4[0], b = b4[1];
        float v[8] = {a.x, a.y, a.z, a.w, b.x, b.y, b.z, b.w};

        bf16x8 shh, s31;
#pragma unroll
        for (int j = 0; j < 8; ++j) {
            float f = v[j];
            unsigned short b1 = f2bf(f);  float r1 = f - bf2f(b1);
            unsigned short b2 = f2bf(r1); float r2 = r1 - bf2f(b2);
            unsigned short b3 = f2bf(r2);
            shh[j] = (short)(lvl ? b2 : b1);
            s31[j] = (short)(lvl ? b1 : b3);
        }
        Bhh[(size_t)ct * 64 + lane] = shh;
        B31[(size_t)ct * 64 + lane] = s31;
        return;
    }

    // ---- proj path ----
    const int b = blockIdx.x;
    for (int i = threadIdx.x; i < IN_DIM * 4; i += 256)
        Ps[i] = ((const float4*)P)[i];
    __syncthreads();

    const int r32   = lane & 31;
    const int khalf = lane >> 5;
    const int row0  = b * 64 + r32;              // second row: row0 + 32
    const int kb    = 128 * wave + 64 * khalf;   // this lane's absolute k base

    float acc0[16], acc1[16];
#pragma unroll
    for (int c = 0; c < 16; ++c) { acc0[c] = 0.0f; acc1[c] = 0.0f; }

    const float4* xr0 = (const float4*)(x + (size_t)row0 * IN_DIM + kb);
    const float4* xr1 = (const float4*)(x + (size_t)(row0 + 32) * IN_DIM + kb);

#pragma unroll 4
    for (int i = 0; i < 16; ++i) {               // 16 float4s = 64 k's
        float4 xv0 = xr0[i], xv1 = xr1[i];
        float xs0[4] = {xv0.x, xv0.y, xv0.z, xv0.w};
        float xs1[4] = {xv1.x, xv1.y, xv1.z, xv1.w};
#pragma unroll
        for (int kk = 0; kk < 4; ++kk) {
#pragma unroll
            for (int q = 0; q < 4; ++q) {
                float4 pv = Ps[(kb + 4 * i + kk) * 4 + q];
                acc0[4 * q + 0] += xs0[kk] * pv.x;
                acc0[4 * q + 1] += xs0[kk] * pv.y;
                acc0[4 * q + 2] += xs0[kk] * pv.z;
                acc0[4 * q + 3] += xs0[kk] * pv.w;
                acc1[4 * q + 0] += xs1[kk] * pv.x;
                acc1[4 * q + 1] += xs1[kk] * pv.y;
                acc1[4 * q + 2] += xs1[kk] * pv.z;
                acc1[4 * q + 3] += xs1[kk] * pv.w;
            }
        }
    }

    const int pslot = wave * 2 + khalf;
#pragma unroll
    for (int c = 0; c < 16; ++c) {
        accs[pslot][r32][c]      = acc0[c];
        accs[pslot][r32 + 32][c] = acc1[c];
    }
    __syncthreads();

    // fold 8 partials + 3-way split + emit A-frags (4 row-tiles per block,
    // one per wave)
    {
        const int rtl  = wave;                   // 0..3
        const int l2   = lane;
        const int m    = l2 & 15;
        const int quad = l2 >> 4;
        const int kh   = (quad & 1) * 8;
        const int lvl  = quad >> 1;
        const int rloc = rtl * 16 + m;

        float v[8];
#pragma unroll
        for (int j = 0; j < 8; ++j) v[j] = 0.0f;
#pragma unroll
        for (int p = 0; p < 8; ++p) {
#pragma unroll
            for (int j = 0; j < 8; ++j) v[j] += accs[p][rloc][kh + j];
        }

        bf16x8 sa, sb;
#pragma unroll
        for (int j = 0; j < 8; ++j) {
            float f = v[j];
            unsigned short b1 = f2bf(f);  float r1 = f - bf2f(b1);
            unsigned short b2 = f2bf(r1); float r2 = r1 - bf2f(b2);
            unsigned short b3 = f2bf(r2);
            sa[j] = (short)(lvl ? b2 : b1);
            sb[j] = (short)(lvl ? b3 : b1);
        }
        AfragA[(size_t)(4 * b + rtl) * 64 + l2] = sa;
        AfragB[(size_t)(4 * b + rtl) * 64 + l2] = sb;
    }
}

// ---------------- K2: MFMA sim + argmax + last-block finalize ---------------
// grid 2048 = 64 rowgrps x 32 codeparts; wave = 4 row-tiles x 16 code-tiles.
// R1 post-mortem: k_scan is latency/occupancy-bound (MfmaUtil 17%, VALUBusy
// 27%, Occupancy 29% -- nothing saturated), NOT L2-BW-bound. So: no LDS
// staging, no barriers in the hot loop (reverted); instead double the block
// count (CODEPARTS 16->32) for 8 blocks/CU = 32 waves/CU potential, and pin
// VGPR<=64 via __launch_bounds__(256,8) so the full wave pool is resident.
// 3 chained bf16 MFMAs per tile (fp32-accurate 3-way split), SW-pipelined
// B-frag loads. Cross-block argmax via device-scope atomicMax(u64); the 32nd
// block to finish a rowgrp decodes part[] -> out[] (no extra dispatch).
__global__ __launch_bounds__(256, 8)
void k_scan(const bf16x8* __restrict__ AfragA, const bf16x8* __restrict__ AfragB,
            const bf16x8* __restrict__ Bhh, const bf16x8* __restrict__ B31,
            unsigned long long* __restrict__ part, unsigned* __restrict__ cnt,
            int* __restrict__ out) {
    __shared__ int s_done;
    const int codepart = blockIdx.x & (CODEPARTS - 1);
    const int rowgrp   = blockIdx.x >> 5;
    const int wave     = threadIdx.x >> 6;
    const int lane     = threadIdx.x & 63;
    const int n        = lane & 15;
    const int quad     = lane >> 4;
    const int rt_base  = rowgrp * 16 + wave * 4;

    bf16x8 Aa[4], Ab[4];
#pragma unroll
    for (int t = 0; t < 4; ++t) {
        Aa[t] = AfragA[(size_t)(rt_base + t) * 64 + lane];
        Ab[t] = AfragB[(size_t)(rt_base + t) * 64 + lane];
    }

    float bestv[4][4];
    int   bestc[4][4];
#pragma unroll
    for (int t = 0; t < 4; ++t)
#pragma unroll
        for (int r = 0; r < 4; ++r) { bestv[t][r] = -INFINITY; bestc[t][r] = 0; }

    const int ct0 = codepart * CT_PER_PART;
    size_t ib = (size_t)ct0 * 64;
    bf16x8 nb1  = Bhh[ib + lane];
    bf16x8 nb1s = Bhh[ib + (lane ^ 32)];
    bf16x8 nb3  = B31[ib + lane];

    for (int c = 0; c < CT_PER_PART; ++c) {
        bf16x8 b1 = nb1, b1s = nb1s, b3 = nb3;
        if (c + 1 < CT_PER_PART) {
            size_t ibn = (size_t)(ct0 + c + 1) * 64;
            nb1  = Bhh[ibn + lane];
            nb1s = Bhh[ibn + (lane ^ 32)];
            nb3  = B31[ibn + lane];
        }
#pragma unroll
        for (int t = 0; t < 4; ++t) {
            f32x4 s = __builtin_amdgcn_mfma_f32_16x16x32_bf16(
                          Aa[t], b1, (f32x4){0.f, 0.f, 0.f, 0.f}, 0, 0, 0);
            s = __builtin_amdgcn_mfma_f32_16x16x32_bf16(Aa[t], b1s, s, 0, 0, 0);
            s = __builtin_amdgcn_mfma_f32_16x16x32_bf16(Ab[t], b3,  s, 0, 0, 0);
#pragma unroll
            for (int r = 0; r < 4; ++r) {
                if (s[r] > bestv[t][r]) { bestv[t][r] = s[r]; bestc[t][r] = c; }
            }
        }
    }

    // reduce over the 16 code-class lanes, then device-scope max per row
#pragma unroll
    for (int t = 0; t < 4; ++t) {
#pragma unroll
        for (int r = 0; r < 4; ++r) {
            unsigned code = (unsigned)(codepart * (CT_PER_PART * 16) +
                                       bestc[t][r] * 16 + n);
            unsigned long long packed =
                ((unsigned long long)fkey(bestv[t][r]) << 32) |
                (unsigned long long)(0xFFFFFFFFu - code);
#pragma unroll
            for (int mk = 1; mk <= 8; mk <<= 1) {
                unsigned long long o = __shfl_xor(packed, mk, 64);
                packed = (o > packed) ? o : packed;
            }
            if (n == 0) {
                int row = (rt_base + t) * 16 + quad * 4 + r;
                atomicMax(&part[row], packed);
            }
        }
    }

    // __syncthreads drains vmcnt -> all this block's atomics are complete
    __syncthreads();
    if (threadIdx.x == 0)
        s_done = (atomicAdd(&cnt[rowgrp], 1u) == (unsigned)(CODEPARTS - 1));
    __syncthreads();

    if (s_done) {
        int row = rowgrp * 256 + threadIdx.x;
        unsigned long long v = atomicAdd(&part[row], 0ull);   // coherent read
        out[row] = (int)(0xFFFFFFFFu - (unsigned)(v & 0xFFFFFFFFull));
    }
}

extern "C" void kernel_launch(void* const* d_in, const int* in_sizes, int n_in,
                              void* d_out, int out_size, void* d_ws, size_t ws_size,
                              hipStream_t stream) {
    const float* x  = (const float*)d_in[0];   // [16384, 512]
    const float* P  = (const float*)d_in[1];   // [512, 16]
    const float* CB = (const float*)d_in[2];   // [8192, 16]
    int* out = (int*)d_out;                    // [16384] int32

    char* ws = (char*)d_ws;
    bf16x8* AfragA = (bf16x8*)(ws + WS_OFF_AFA);
    bf16x8* AfragB = (bf16x8*)(ws + WS_OFF_AFB);
    bf16x8* Bhh    = (bf16x8*)(ws + WS_OFF_BHH);
    bf16x8* B31    = (bf16x8*)(ws + WS_OFF_B31);
    unsigned long long* part = (unsigned long long*)(ws + WS_OFF_PART);
    unsigned* cnt  = (unsigned*)(ws + WS_OFF_CNT);

    k_front<<<PROJ_BLOCKS + PREP_BLOCKS, 256, 0, stream>>>(
        x, P, CB, AfragA, AfragB, Bhh, B31, part, cnt);            // 384 blocks
    k_scan<<<N_ROWGRP * CODEPARTS, 256, 0, stream>>>(
        AfragA, AfragB, Bhh, B31, part, cnt, out);                 // 2048 blocks
}

// Round 3
// 118.640 us; speedup vs baseline: 2.4846x; 2.4846x over previous
//
#include <hip/hip_runtime.h>
#include <stdint.h>

#define N_ROWS   16384
#define IN_DIM   512
#define CB_DIM   16
#define CB_VOCAB 8192

// ---- K1 geometry
#define PROJ_BLOCKS 512                          // 32 rows each, full K
#define PREP_BLOCKS 128                          // 4 code-tiles each

// ---- scan geometry
#define N_RT   (N_ROWS / 16)                     // 1024 row-tiles
#define N_CT   (CB_VOCAB / 16)                   // 512 code-tiles
#define CODEPARTS 32
#define CT_PER_PART (N_CT / CODEPARTS)           // 16
#define N_ROWGRP 64                              // 256 rows per rowgrp

// ---- workspace layout (bytes), ~3.2 MB
#define WS_OFF_AFA  0                            // A-frag [A1|A2]: 1 MB
#define WS_OFF_AFB  (1u << 20)                   // A-frag [A1|A3]: 1 MB
#define WS_OFF_BHH  (2u << 20)                   // B-frag [B1;B2]: 512 KB
#define WS_OFF_B31  ((2u << 20) + (512u << 10))  // B-frag [B3;B1]: 512 KB
#define WS_OFF_PART (3u << 20)                   // u64[16384]: 128 KB
#define WS_OFF_CNT  ((3u << 20) + (128u << 10))  // u32[64]

typedef __attribute__((ext_vector_type(8))) short bf16x8;
typedef __attribute__((ext_vector_type(4))) float f32x4;

// monotone float -> uint32 key (order-preserving)
__device__ __forceinline__ unsigned fkey(float f) {
    unsigned u = __float_as_uint(f);
    return (u & 0x80000000u) ? ~u : (u | 0x80000000u);
}

// fp32 -> bf16 bits, round-to-nearest-even
__device__ __forceinline__ unsigned short f2bf(float f) {
    unsigned u = __float_as_uint(f);
    return (unsigned short)((u + 0x7FFFu + ((u >> 16) & 1u)) >> 16);
}
__device__ __forceinline__ float bf2f(unsigned short h) {
    return __uint_as_float(((unsigned)h) << 16);
}

// ---------------- K1: proj + fold + A-frag (blocks 0..511); CB prep + init
// (blocks 512..639).
// R2 post-mortem: the old per-lane-row x read (2048 B lane stride) was
// uncoalesced -- 64 cache lines per wave-load, ~1 TB/s achieved, and k_front
// sat at ~32 us regardless of structure. New proj: per 64-k chunk, the block
// stages x[32 rows][64 k] into LDS with fully-coalesced 256 B/row segments
// (reg-staged, issue-early/write-late, double-buffered, 1 barrier/chunk).
// Compute keeps the 8-partial scheme: thread (r32, s) accumulates k in
// {g*64 + s*8 .. +8} over all chunks g into acc[16]; partials folded as
// before. LDS cols XOR-swizzled (s ^ ((r>>3)&3)) so the strided compute-side
// ds_read_b128 is bank-conflict-free. accs[] unions with the dead x-staging
// buffer: LDS 52 KB -> 3 blocks/CU (12 waves vs 8).
__global__ __launch_bounds__(256, 3)
void k_front(const float* __restrict__ x, const float* __restrict__ P,
             const float* __restrict__ CB,
             bf16x8* __restrict__ AfragA, bf16x8* __restrict__ AfragB,
             bf16x8* __restrict__ Bhh, bf16x8* __restrict__ B31,
             unsigned long long* __restrict__ part, unsigned* __restrict__ cnt) {
    __shared__ float4 Ps[IN_DIM * 4];            // P [512][16]: 32 KB
    // union: xs[2][32][68] floats (17 KB, chunk double-buffer) during the
    // k-loop; accs[8][32][20] floats (20 KB) afterwards.
    __shared__ __align__(16) float uni[8 * 32 * 20];

    const int wave = threadIdx.x >> 6;
    const int lane = threadIdx.x & 63;

    if (blockIdx.x >= PROJ_BLOCKS) {
        // ---- prep path: zero part/cnt, build CB B-frags ----
        const int pb = blockIdx.x - PROJ_BLOCKS;
        if (threadIdx.x < 128) part[pb * 128 + threadIdx.x] = 0ull;
        if (pb == 0 && threadIdx.x < 64) cnt[threadIdx.x] = 0u;

        const int ct   = pb * 4 + wave;
        const int n    = lane & 15;
        const int quad = lane >> 4;
        const int kh   = (quad & 1) * 8;
        const int lvl  = quad >> 1;
        const int code = ct * 16 + n;

        const float4* b4 = (const float4*)(CB + (size_t)code * CB_DIM + kh);
        float4 a = b4[0], b = b4[1];
        float v[8] = {a.x, a.y, a.z, a.w, b.x, b.y, b.z, b.w};

        bf16x8 shh, s31;
#pragma unroll
        for (int j = 0; j < 8; ++j) {
            float f = v[j];
            unsigned short b1 = f2bf(f);  float r1 = f - bf2f(b1);
            unsigned short b2 = f2bf(r1); float r2 = r1 - bf2f(b2);
            unsigned short b3 = f2bf(r2);
            shh[j] = (short)(lvl ? b2 : b1);
            s31[j] = (short)(lvl ? b1 : b3);
        }
        Bhh[(size_t)ct * 64 + lane] = shh;
        B31[(size_t)ct * 64 + lane] = s31;
        return;
    }

    // ---- proj path ----
    const int b   = blockIdx.x;
    const int tid = threadIdx.x;

#define XS(bf, r, c) uni[((bf) * 2176) + (r) * 68 + (c)]

    for (int i = tid; i < IN_DIM * 4; i += 256)
        Ps[i] = ((const float4*)P)[i];

    // staging role: thread t loads row (t>>3), 32 B at col (t&7)*8 floats.
    // Wave = 8 rows x 256 B contiguous segments -> fully coalesced.
    const int lr   = tid >> 3;
    const int lc   = tid & 7;
    const int wcol = (lc ^ ((lr >> 3) & 3)) << 3;     // XOR-swizzled col
    const float4* xg = (const float4*)(x + (size_t)(b * 32 + lr) * IN_DIM);

    // chunk 0: load + write (nobody reads xs yet; Ps region disjoint)
    float4 c0a = xg[lc * 2], c0b = xg[lc * 2 + 1];
    *(float4*)&XS(0, lr, wcol)     = c0a;
    *(float4*)&XS(0, lr, wcol + 4) = c0b;
    // chunk 1: issue loads now, write at top of iter 0
    float4 n0 = xg[16 + lc * 2], n1 = xg[16 + lc * 2 + 1];
    __syncthreads();                                  // Ps + xs[0] visible

    // compute role: thread (r32, s) owns row r32, k-slot s
    const int r32  = tid & 31;
    const int s    = tid >> 5;                        // 0..7 (pslot)
    const int rcol = (s ^ ((r32 >> 3) & 3)) << 3;     // matching swizzle

    float acc[16];
#pragma unroll
    for (int c = 0; c < 16; ++c) acc[c] = 0.0f;

    for (int g = 0; g < 8; ++g) {
        // write-late for chunk g+1 (its buffer was last read in iter g-1,
        // before that iter's barrier), then issue loads for chunk g+2.
        if (g < 7) {
            *(float4*)&XS((g + 1) & 1, lr, wcol)     = n0;
            *(float4*)&XS((g + 1) & 1, lr, wcol + 4) = n1;
            if (g < 6) {
                n0 = xg[(g + 2) * 16 + lc * 2];
                n1 = xg[(g + 2) * 16 + lc * 2 + 1];
            }
        }

        float4 xa = *(const float4*)&XS(g & 1, r32, rcol);
        float4 xb = *(const float4*)&XS(g & 1, r32, rcol + 4);
        float xv[8] = {xa.x, xa.y, xa.z, xa.w, xb.x, xb.y, xb.z, xb.w};
        const int kb4 = (g * 64 + s * 8) * 4;
#pragma unroll
        for (int j = 0; j < 8; ++j) {
#pragma unroll
            for (int q = 0; q < 4; ++q) {
                float4 pv = Ps[kb4 + j * 4 + q];      // wave-uniform: broadcast
                acc[4 * q + 0] += xv[j] * pv.x;
                acc[4 * q + 1] += xv[j] * pv.y;
                acc[4 * q + 2] += xv[j] * pv.z;
                acc[4 * q + 3] += xv[j] * pv.w;
            }
        }
        __syncthreads();
    }

    // xs dead (final barrier passed) -> reuse uni as accs[8][32][20]
    float (*accs)[32][20] = (float(*)[32][20])uni;
#pragma unroll
    for (int c = 0; c < 16; ++c) accs[s][r32][c] = acc[c];
    __syncthreads();

    // fold 8 partials + 3-way split + emit A-frags (2 row-tiles per block)
    if (tid < 128) {
        const int rtl  = tid >> 6;                   // 0/1
        const int l2   = tid & 63;
        const int m    = l2 & 15;
        const int quad = l2 >> 4;
        const int kh   = (quad & 1) * 8;
        const int lvl  = quad >> 1;
        const int rloc = rtl * 16 + m;

        float v[8];
#pragma unroll
        for (int j = 0; j < 8; ++j) v[j] = 0.0f;
#pragma unroll
        for (int p = 0; p < 8; ++p) {
#pragma unroll
            for (int j = 0; j < 8; ++j) v[j] += accs[p][rloc][kh + j];
        }

        bf16x8 sa, sb;
#pragma unroll
        for (int j = 0; j < 8; ++j) {
            float f = v[j];
            unsigned short b1 = f2bf(f);  float r1 = f - bf2f(b1);
            unsigned short b2 = f2bf(r1); float r2 = r1 - bf2f(b2);
            unsigned short b3 = f2bf(r2);
            sa[j] = (short)(lvl ? b2 : b1);
            sb[j] = (short)(lvl ? b3 : b1);
        }
        AfragA[(size_t)(2 * b + rtl) * 64 + l2] = sa;
        AfragB[(size_t)(2 * b + rtl) * 64 + l2] = sb;
    }
#undef XS
}

// ---------------- K2: MFMA sim + argmax + last-block finalize ---------------
// grid 2048 = 64 rowgrps x 32 codeparts; wave = 4 row-tiles x 16 code-tiles.
// R2 post-mortem: __launch_bounds__(256,8) forced VGPR 64->32 and spilled
// ~800 MB of scratch to HBM (FETCH 508 MB) -> 219 us. Revert to (256,4):
// R1 proved this exact loop compiles to 64 VGPR, which already HW-permits
// 8 waves/SIMD -- the grid (now 2048 = 8 blocks/CU) is what unlocks full
// residency, no register cap needed.
// 3 chained bf16 MFMAs per tile (fp32-accurate 3-way split), SW-pipelined
// B-frag loads. Cross-block argmax via device-scope atomicMax(u64); the 32nd
// block to finish a rowgrp decodes part[] -> out[] (no extra dispatch).
__global__ __launch_bounds__(256, 4)
void k_scan(const bf16x8* __restrict__ AfragA, const bf16x8* __restrict__ AfragB,
            const bf16x8* __restrict__ Bhh, const bf16x8* __restrict__ B31,
            unsigned long long* __restrict__ part, unsigned* __restrict__ cnt,
            int* __restrict__ out) {
    __shared__ int s_done;
    const int codepart = blockIdx.x & (CODEPARTS - 1);
    const int rowgrp   = blockIdx.x >> 5;
    const int wave     = threadIdx.x >> 6;
    const int lane     = threadIdx.x & 63;
    const int n        = lane & 15;
    const int quad     = lane >> 4;
    const int rt_base  = rowgrp * 16 + wave * 4;

    bf16x8 Aa[4], Ab[4];
#pragma unroll
    for (int t = 0; t < 4; ++t) {
        Aa[t] = AfragA[(size_t)(rt_base + t) * 64 + lane];
        Ab[t] = AfragB[(size_t)(rt_base + t) * 64 + lane];
    }

    float bestv[4][4];
    int   bestc[4][4];
#pragma unroll
    for (int t = 0; t < 4; ++t)
#pragma unroll
        for (int r = 0; r < 4; ++r) { bestv[t][r] = -INFINITY; bestc[t][r] = 0; }

    const int ct0 = codepart * CT_PER_PART;
    size_t ib = (size_t)ct0 * 64;
    bf16x8 nb1  = Bhh[ib + lane];
    bf16x8 nb1s = Bhh[ib + (lane ^ 32)];
    bf16x8 nb3  = B31[ib + lane];

    for (int c = 0; c < CT_PER_PART; ++c) {
        bf16x8 b1 = nb1, b1s = nb1s, b3 = nb3;
        if (c + 1 < CT_PER_PART) {
            size_t ibn = (size_t)(ct0 + c + 1) * 64;
            nb1  = Bhh[ibn + lane];
            nb1s = Bhh[ibn + (lane ^ 32)];
            nb3  = B31[ibn + lane];
        }
#pragma unroll
        for (int t = 0; t < 4; ++t) {
            f32x4 s = __builtin_amdgcn_mfma_f32_16x16x32_bf16(
                          Aa[t], b1, (f32x4){0.f, 0.f, 0.f, 0.f}, 0, 0, 0);
            s = __builtin_amdgcn_mfma_f32_16x16x32_bf16(Aa[t], b1s, s, 0, 0, 0);
            s = __builtin_amdgcn_mfma_f32_16x16x32_bf16(Ab[t], b3,  s, 0, 0, 0);
#pragma unroll
            for (int r = 0; r < 4; ++r) {
                if (s[r] > bestv[t][r]) { bestv[t][r] = s[r]; bestc[t][r] = c; }
            }
        }
    }

    // reduce over the 16 code-class lanes, then device-scope max per row
#pragma unroll
    for (int t = 0; t < 4; ++t) {
#pragma unroll
        for (int r = 0; r < 4; ++r) {
            unsigned code = (unsigned)(codepart * (CT_PER_PART * 16) +
                                       bestc[t][r] * 16 + n);
            unsigned long long packed =
                ((unsigned long long)fkey(bestv[t][r]) << 32) |
                (unsigned long long)(0xFFFFFFFFu - code);
#pragma unroll
            for (int mk = 1; mk <= 8; mk <<= 1) {
                unsigned long long o = __shfl_xor(packed, mk, 64);
                packed = (o > packed) ? o : packed;
            }
            if (n == 0) {
                int row = (rt_base + t) * 16 + quad * 4 + r;
                atomicMax(&part[row], packed);
            }
        }
    }

    // __syncthreads drains vmcnt -> all this block's atomics are complete
    __syncthreads();
    if (threadIdx.x == 0)
        s_done = (atomicAdd(&cnt[rowgrp], 1u) == (unsigned)(CODEPARTS - 1));
    __syncthreads();

    if (s_done) {
        int row = rowgrp * 256 + threadIdx.x;
        unsigned long long v = atomicAdd(&part[row], 0ull);   // coherent read
        out[row] = (int)(0xFFFFFFFFu - (unsigned)(v & 0xFFFFFFFFull));
    }
}

extern "C" void kernel_launch(void* const* d_in, const int* in_sizes, int n_in,
                              void* d_out, int out_size, void* d_ws, size_t ws_size,
                              hipStream_t stream) {
    const float* x  = (const float*)d_in[0];   // [16384, 512]
    const float* P  = (const float*)d_in[1];   // [512, 16]
    const float* CB = (const float*)d_in[2];   // [8192, 16]
    int* out = (int*)d_out;                    // [16384] int32

    char* ws = (char*)d_ws;
    bf16x8* AfragA = (bf16x8*)(ws + WS_OFF_AFA);
    bf16x8* AfragB = (bf16x8*)(ws + WS_OFF_AFB);
    bf16x8* Bhh    = (bf16x8*)(ws + WS_OFF_BHH);
    bf16x8* B31    = (bf16x8*)(ws + WS_OFF_B31);
    unsigned long long* part = (unsigned long long*)(ws + WS_OFF_PART);
    unsigned* cnt  = (unsigned*)(ws + WS_OFF_CNT);

    k_front<<<PROJ_BLOCKS + PREP_BLOCKS, 256, 0, stream>>>(
        x, P, CB, AfragA, AfragB, Bhh, B31, part, cnt);            // 640 blocks
    k_scan<<<N_ROWGRP * CODEPARTS, 256, 0, stream>>>(
        AfragA, AfragB, Bhh, B31, part, cnt, out);                 // 2048 blocks
}